// Round 1
// baseline (541.696 us; speedup 1.0000x reference)
//
#include <hip/hip_runtime.h>

// ---------------------------------------------------------------------------
// CausalSelfAttention (GPT-2 style), MI355X / gfx950
//   qkv = x @ w_attn + b_attn            (bf16 MFMA GEMM, 128x128 tile)
//   y   = causal_flash_attention(q,k,v)  (16x16x32 bf16 MFMA, online softmax)
//   out = y @ w_proj + b_proj            (bf16 MFMA GEMM, f32 out)
// B=2 T=4096 C=768 H=12 hd=64
// ---------------------------------------------------------------------------

#define DEVFN __device__ __forceinline__

typedef __attribute__((ext_vector_type(8))) short   short8;
typedef __attribute__((ext_vector_type(4))) short   short4v;
typedef __attribute__((ext_vector_type(8))) __bf16  bf16x8;
typedef __attribute__((ext_vector_type(4))) float   f32x4;

constexpr int BATCH = 2;
constexpr int T     = 4096;
constexpr int CDIM  = 768;
constexpr int NH    = 12;
constexpr int HD    = 64;      // head dim
constexpr int M_TOK = BATCH * T;   // 8192
constexpr int N_QKV = 3 * CDIM;    // 2304

DEVFN short f2bf(float f) {            // RNE float -> bf16 bits
  unsigned u = __builtin_bit_cast(unsigned, f);
  u += 0x7fffu + ((u >> 16) & 1u);
  return (short)(u >> 16);
}
DEVFN float bf2f(short s) {
  return __builtin_bit_cast(float, ((unsigned)(unsigned short)s) << 16);
}
DEVFN f32x4 mfma16(short8 a, short8 b, f32x4 c) {
  return __builtin_amdgcn_mfma_f32_16x16x32_bf16(
      __builtin_bit_cast(bf16x8, a), __builtin_bit_cast(bf16x8, b), c, 0, 0, 0);
}

// ---------------------------------------------------------------------------
// cast f32 -> bf16, vectorized (4 elems / thread)
// ---------------------------------------------------------------------------
__global__ void cast_f32_bf16(const float* __restrict__ in,
                              short* __restrict__ out, int n) {
  int i = (blockIdx.x * blockDim.x + threadIdx.x) * 4;
  if (i >= n) return;
  f32x4 v = *reinterpret_cast<const f32x4*>(in + i);
  short4v o;
#pragma unroll
  for (int j = 0; j < 4; ++j) o[j] = f2bf(v[j]);
  *reinterpret_cast<short4v*>(out + i) = o;
}

// ---------------------------------------------------------------------------
// transpose-cast: in f32 [R][Cc] -> out bf16 [Cc][R]   (32x32 LDS tiles)
// ---------------------------------------------------------------------------
__global__ void transpose_cast(const float* __restrict__ in,
                               short* __restrict__ out, int R, int Cc) {
  __shared__ float tile[32][33];
  int c0 = blockIdx.x * 32, r0 = blockIdx.y * 32;
  int tx = threadIdx.x, ty = threadIdx.y;      // block (32, 8)
#pragma unroll
  for (int j = 0; j < 32; j += 8) {
    int r = r0 + ty + j, c = c0 + tx;
    tile[ty + j][tx] = (r < R && c < Cc) ? in[(size_t)r * Cc + c] : 0.f;
  }
  __syncthreads();
#pragma unroll
  for (int j = 0; j < 32; j += 8) {
    int r = r0 + tx, c = c0 + ty + j;
    if (c < Cc && r < R) out[(size_t)c * R + r] = f2bf(tile[tx][ty + j]);
  }
}

// ---------------------------------------------------------------------------
// GEMM: C[M][N] = A[M][K] @ Bt[N][K]^T + bias[N]
// A, Bt bf16; OUT_BF16 selects bf16 or f32 output.
// 128x128 block tile, BK=32, 4 waves (2x2), each wave 64x64 = 4x4 MFMA frags.
// ---------------------------------------------------------------------------
template <int OUT_BF16>
__global__ __launch_bounds__(256)
void gemm_bt(const short* __restrict__ A, const short* __restrict__ Bt,
             const float* __restrict__ bias, void* __restrict__ Cout,
             int M, int N, int K) {
  constexpr int BM = 128, BN = 128, BK = 32, LDP = BK + 8;  // pad 8 -> 80B rows
  __shared__ short As[BM * LDP];
  __shared__ short Bs[BN * LDP];
  const int bm = blockIdx.x, bn = blockIdx.y;
  const int tid = threadIdx.x;
  const int lane = tid & 63, wid = tid >> 6;
  const int wm = wid >> 1, wn = wid & 1;
  const int lr = lane & 15, lh = lane >> 4;

  f32x4 acc[4][4] = {};

  const short* Abase = A + (size_t)(bm * BM) * K;
  const short* Bbase = Bt + (size_t)(bn * BN) * K;

  for (int k0 = 0; k0 < K; k0 += BK) {
    __syncthreads();
#pragma unroll
    for (int i = 0; i < 2; ++i) {        // 512 chunks of 8 bf16, 2 per thread
      int c = tid + i * 256;
      int row = c >> 2, col = (c & 3) << 3;
      *reinterpret_cast<short8*>(&As[row * LDP + col]) =
          *reinterpret_cast<const short8*>(Abase + (size_t)row * K + k0 + col);
      *reinterpret_cast<short8*>(&Bs[row * LDP + col]) =
          *reinterpret_cast<const short8*>(Bbase + (size_t)row * K + k0 + col);
    }
    __syncthreads();

    short8 af[4], bfr[4];
#pragma unroll
    for (int m = 0; m < 4; ++m)
      af[m] = *reinterpret_cast<const short8*>(
          &As[(wm * 64 + m * 16 + lr) * LDP + lh * 8]);
#pragma unroll
    for (int n = 0; n < 4; ++n)
      bfr[n] = *reinterpret_cast<const short8*>(
          &Bs[(wn * 64 + n * 16 + lr) * LDP + lh * 8]);
#pragma unroll
    for (int m = 0; m < 4; ++m)
#pragma unroll
      for (int n = 0; n < 4; ++n)
        acc[m][n] = mfma16(af[m], bfr[n], acc[m][n]);
  }

  // epilogue: C/D layout col = lane&15, row = 4*(lane>>4)+r  [m89 verified]
#pragma unroll
  for (int m = 0; m < 4; ++m) {
#pragma unroll
    for (int n = 0; n < 4; ++n) {
#pragma unroll
      for (int r = 0; r < 4; ++r) {
        int row = bm * BM + wm * 64 + m * 16 + lh * 4 + r;
        int col = bn * BN + wn * 64 + n * 16 + lr;
        float v = acc[m][n][r] + bias[col];
        if (OUT_BF16)
          ((short*)Cout)[(size_t)row * N + col] = f2bf(v);
        else
          ((float*)Cout)[(size_t)row * N + col] = v;
      }
    }
  }
}

// ---------------------------------------------------------------------------
// Causal flash attention.
// Grid: (T/64, B*H). Block: 256 thr = 4 waves; wave w owns 16 q-rows.
// K/V 64-row tiles staged in LDS (V transposed). Online softmax per q-row.
// Scale 1/8 folded into Q (exact pow2 in bf16).
// ---------------------------------------------------------------------------
__global__ __launch_bounds__(256)
void attn_kernel(const short* __restrict__ qkv, short* __restrict__ y) {
  constexpr int LKD = HD + 8;  // 72 elems = 144B rows (bank-spread)
  __shared__ short K_lds[64 * LKD];
  __shared__ short Vt_lds[64 * LKD];     // [d][k]
  __shared__ short P_lds[4 * 16 * LKD];  // per-wave P[16][64]

  const int qb = (int)gridDim.x - 1 - (int)blockIdx.x;  // heavy blocks first
  const int bh = blockIdx.y;
  const int b = bh / NH, h = bh % NH;
  const int tid = threadIdx.x, wid = tid >> 6, lane = tid & 63;
  const int lr = lane & 15, lh = lane >> 4;
  const int qbase = qb * 64 + wid * 16;

  const short* qkv_b = qkv + (size_t)b * T * N_QKV;

  // Q fragments (A-frag: row = lane&15, k = 8*(lane>>4)+i), pre-scaled by 1/8
  short8 qf[2];
  {
    const short* qp = qkv_b + (size_t)(qbase + lr) * N_QKV + h * HD + lh * 8;
#pragma unroll
    for (int c2 = 0; c2 < 2; ++c2) {
      short8 raw = *reinterpret_cast<const short8*>(qp + c2 * 32);
#pragma unroll
      for (int i = 0; i < 8; ++i) raw[i] = f2bf(bf2f(raw[i]) * 0.125f);
      qf[c2] = raw;
    }
  }

  f32x4 oacc[4] = {};
  float mrow[4], lrow[4];
#pragma unroll
  for (int r = 0; r < 4; ++r) { mrow[r] = -1e30f; lrow[r] = 0.f; }

  short* pl = &P_lds[wid * 16 * LKD];

  for (int kb = 0; kb <= qb; ++kb) {
    __syncthreads();  // prior iteration's readers done
#pragma unroll
    for (int i = 0; i < 2; ++i) {  // stage K row-major, V transposed
      int c = tid + i * 256;
      int row = c >> 3, col = (c & 7) << 3;
      const short* kp =
          qkv_b + (size_t)(kb * 64 + row) * N_QKV + CDIM + h * HD + col;
      *reinterpret_cast<short8*>(&K_lds[row * LKD + col]) =
          *reinterpret_cast<const short8*>(kp);
      short8 vv = *reinterpret_cast<const short8*>(kp + CDIM);
#pragma unroll
      for (int j = 0; j < 8; ++j) Vt_lds[(col + j) * LKD + row] = vv[j];
    }
    __syncthreads();

    // S[16 q][64 k] = Q @ K^T  (4 k-tiles x 2 K=32 chunks)
    f32x4 s[4];
#pragma unroll
    for (int kt = 0; kt < 4; ++kt) {
      f32x4 z = {0.f, 0.f, 0.f, 0.f};
      short8 kf0 = *reinterpret_cast<const short8*>(
          &K_lds[(kt * 16 + lr) * LKD + lh * 8]);
      short8 kf1 = *reinterpret_cast<const short8*>(
          &K_lds[(kt * 16 + lr) * LKD + 32 + lh * 8]);
      z = mfma16(qf[0], kf0, z);
      z = mfma16(qf[1], kf1, z);
      s[kt] = z;
    }
    if (kb == qb) {  // diagonal block: causal mask
#pragma unroll
      for (int kt = 0; kt < 4; ++kt)
#pragma unroll
        for (int r = 0; r < 4; ++r)
          if (kb * 64 + kt * 16 + lr > qbase + lh * 4 + r) s[kt][r] = -1e30f;
    }

    // online softmax (rows live across lanes 0..15 of each 16-lane group)
    float p[4][4], alpha[4];
#pragma unroll
    for (int r = 0; r < 4; ++r) {
      float mx = fmaxf(fmaxf(s[0][r], s[1][r]), fmaxf(s[2][r], s[3][r]));
      mx = fmaxf(mx, __shfl_xor(mx, 1));
      mx = fmaxf(mx, __shfl_xor(mx, 2));
      mx = fmaxf(mx, __shfl_xor(mx, 4));
      mx = fmaxf(mx, __shfl_xor(mx, 8));
      float mnew = fmaxf(mrow[r], mx);
      alpha[r] = exp2f((mrow[r] - mnew) * 1.44269504f);
      mrow[r] = mnew;
      float ps = 0.f;
#pragma unroll
      for (int kt = 0; kt < 4; ++kt) {
        float pv = exp2f((s[kt][r] - mnew) * 1.44269504f);
        p[kt][r] = pv;
        ps += pv;
      }
      ps += __shfl_xor(ps, 1);
      ps += __shfl_xor(ps, 2);
      ps += __shfl_xor(ps, 4);
      ps += __shfl_xor(ps, 8);
      lrow[r] = lrow[r] * alpha[r] + ps;
    }
#pragma unroll
    for (int n = 0; n < 4; ++n)
#pragma unroll
      for (int r = 0; r < 4; ++r) oacc[n][r] *= alpha[r];

    // P -> LDS (C-layout scatter), re-read as A-frags. Same-wave LDS is
    // in-order in HW; may-alias stops compiler reorder; wave_barrier pins it.
#pragma unroll
    for (int kt = 0; kt < 4; ++kt)
#pragma unroll
      for (int r = 0; r < 4; ++r)
        pl[(lh * 4 + r) * LKD + kt * 16 + lr] = f2bf(p[kt][r]);
    __builtin_amdgcn_wave_barrier();
    short8 pf0 = *reinterpret_cast<const short8*>(&pl[lr * LKD + lh * 8]);
    short8 pf1 = *reinterpret_cast<const short8*>(&pl[lr * LKD + 32 + lh * 8]);

    // O[16][64] += P[16][64] @ V[64][64]   (B-frag from transposed V)
#pragma unroll
    for (int n = 0; n < 4; ++n) {
      short8 vf0 = *reinterpret_cast<const short8*>(
          &Vt_lds[(n * 16 + lr) * LKD + lh * 8]);
      short8 vf1 = *reinterpret_cast<const short8*>(
          &Vt_lds[(n * 16 + lr) * LKD + 32 + lh * 8]);
      oacc[n] = mfma16(pf0, vf0, oacc[n]);
      oacc[n] = mfma16(pf1, vf1, oacc[n]);
    }
  }

  // normalize + write y (bf16, [B*T][C] with head offset)
#pragma unroll
  for (int r = 0; r < 4; ++r) {
    float inv = 1.0f / lrow[r];
    int qrow = qbase + lh * 4 + r;
    short* yp = y + (size_t)(b * T + qrow) * CDIM + h * HD;
#pragma unroll
    for (int n = 0; n < 4; ++n) yp[n * 16 + lr] = f2bf(oacc[n][r] * inv);
  }
}

// ---------------------------------------------------------------------------
extern "C" void kernel_launch(void* const* d_in, const int* in_sizes, int n_in,
                              void* d_out, int out_size, void* d_ws,
                              size_t ws_size, hipStream_t stream) {
  const float* x      = (const float*)d_in[0];
  const float* w_attn = (const float*)d_in[1];
  const float* b_attn = (const float*)d_in[2];
  const float* w_proj = (const float*)d_in[3];
  const float* b_proj = (const float*)d_in[4];
  float* out = (float*)d_out;

  // workspace layout (bf16 shorts); y reuses xb (xb dead after QKV GEMM)
  short* xb   = (short*)d_ws;                       // 8192*768
  short* watT = xb + (size_t)M_TOK * CDIM;          // 2304*768
  short* wpT  = watT + (size_t)N_QKV * CDIM;        // 768*768
  short* qkv  = wpT + (size_t)CDIM * CDIM;          // 8192*2304
  short* yb   = xb;

  {  // x -> bf16
    int n = M_TOK * CDIM;
    cast_f32_bf16<<<n / 4 / 256, 256, 0, stream>>>(x, xb, n);
  }
  // weights -> bf16, transposed to [N][K]
  transpose_cast<<<dim3(N_QKV / 32, CDIM / 32), dim3(32, 8), 0, stream>>>(
      w_attn, watT, CDIM, N_QKV);
  transpose_cast<<<dim3(CDIM / 32, CDIM / 32), dim3(32, 8), 0, stream>>>(
      w_proj, wpT, CDIM, CDIM);

  // qkv = x @ w_attn + b_attn   (bf16 out)
  gemm_bt<1><<<dim3(M_TOK / 128, N_QKV / 128), 256, 0, stream>>>(
      xb, watT, b_attn, qkv, M_TOK, N_QKV, CDIM);

  // flash attention
  attn_kernel<<<dim3(T / 64, BATCH * NH), 256, 0, stream>>>(qkv, yb);

  // out = y @ w_proj + b_proj   (f32 out)
  gemm_bt<0><<<dim3(M_TOK / 128, CDIM / 128), 256, 0, stream>>>(
      yb, wpT, b_proj, out, M_TOK, CDIM, CDIM);
}

// Round 2
// 372.911 us; speedup vs baseline: 1.4526x; 1.4526x over previous
//
#include <hip/hip_runtime.h>

// ---------------------------------------------------------------------------
// CausalSelfAttention (GPT-2 style), MI355X / gfx950
//   qkv GEMM writes Q,K normally and V *transposed* (vt[bh][d][t]) in epilogue
//   flash attention: 4 waves x 32 q-rows, KVBLK=64, DPP softmax reductions
//   proj GEMM f32 out
// B=2 T=4096 C=768 H=12 hd=64
// ---------------------------------------------------------------------------

#define DEVFN __device__ __forceinline__

typedef __attribute__((ext_vector_type(8))) short   short8;
typedef __attribute__((ext_vector_type(4))) short   short4v;
typedef __attribute__((ext_vector_type(8))) __bf16  bf16x8;
typedef __attribute__((ext_vector_type(4))) float   f32x4;

constexpr int BATCH = 2;
constexpr int T     = 4096;
constexpr int CDIM  = 768;
constexpr int NH    = 12;
constexpr int HD    = 64;
constexpr int M_TOK = BATCH * T;   // 8192
constexpr int N_QKV = 3 * CDIM;    // 2304
constexpr int N_QK  = 2 * CDIM;    // 1536
constexpr float LOG2E = 1.44269504f;

DEVFN short f2bf(float f) {            // RNE float -> bf16 bits
  unsigned u = __builtin_bit_cast(unsigned, f);
  u += 0x7fffu + ((u >> 16) & 1u);
  return (short)(u >> 16);
}
DEVFN float bf2f(short s) {
  return __builtin_bit_cast(float, ((unsigned)(unsigned short)s) << 16);
}
DEVFN f32x4 mfma16(short8 a, short8 b, f32x4 c) {
  return __builtin_amdgcn_mfma_f32_16x16x32_bf16(
      __builtin_bit_cast(bf16x8, a), __builtin_bit_cast(bf16x8, b), c, 0, 0, 0);
}

// DPP 16-lane (one DPP row) reductions — VALU pipe, no LDS traffic.
template <int CTRL>
DEVFN float dpp_mv(float x) {
  return __builtin_bit_cast(
      float, __builtin_amdgcn_mov_dpp(__builtin_bit_cast(int, x), CTRL, 0xf,
                                      0xf, true));
}
DEVFN float red16_max(float x) {
  x = fmaxf(x, dpp_mv<0xB1>(x));   // quad_perm [1,0,3,2]
  x = fmaxf(x, dpp_mv<0x4E>(x));   // quad_perm [2,3,0,1]
  x = fmaxf(x, dpp_mv<0x141>(x));  // row_half_mirror
  x = fmaxf(x, dpp_mv<0x140>(x));  // row_mirror
  return x;
}
DEVFN float red16_sum(float x) {
  x += dpp_mv<0xB1>(x);
  x += dpp_mv<0x4E>(x);
  x += dpp_mv<0x141>(x);
  x += dpp_mv<0x140>(x);
  return x;
}

// ---------------------------------------------------------------------------
__global__ void cast_f32_bf16(const float* __restrict__ in,
                              short* __restrict__ out, int n) {
  int i = (blockIdx.x * blockDim.x + threadIdx.x) * 4;
  if (i >= n) return;
  f32x4 v = *reinterpret_cast<const f32x4*>(in + i);
  short4v o;
#pragma unroll
  for (int j = 0; j < 4; ++j) o[j] = f2bf(v[j]);
  *reinterpret_cast<short4v*>(out + i) = o;
}

__global__ void transpose_cast(const float* __restrict__ in,
                               short* __restrict__ out, int R, int Cc) {
  __shared__ float tile[32][33];
  int c0 = blockIdx.x * 32, r0 = blockIdx.y * 32;
  int tx = threadIdx.x, ty = threadIdx.y;  // block (32, 8)
#pragma unroll
  for (int j = 0; j < 32; j += 8) {
    int r = r0 + ty + j, c = c0 + tx;
    tile[ty + j][tx] = (r < R && c < Cc) ? in[(size_t)r * Cc + c] : 0.f;
  }
  __syncthreads();
#pragma unroll
  for (int j = 0; j < 32; j += 8) {
    int r = r0 + tx, c = c0 + ty + j;
    if (c < Cc && r < R) out[(size_t)c * R + r] = f2bf(tile[tx][ty + j]);
  }
}

// ---------------------------------------------------------------------------
// GEMM: C[M][N] = A[M][K] @ Bt[N][K]^T + bias[N]
// MODE 0: f32 plain output.
// MODE 2: qkv split — cols [0,1536) -> qk bf16 [M][1536];
//         cols [1536,2304) (= V) -> vt bf16 [(b*NH+h)*64+d][T] (transposed).
// ---------------------------------------------------------------------------
template <int MODE>
__global__ __launch_bounds__(256)
void gemm_bt(const short* __restrict__ A, const short* __restrict__ Bt,
             const float* __restrict__ bias, float* __restrict__ Cf,
             short* __restrict__ qk_out, short* __restrict__ vt_out,
             int M, int N, int K) {
  constexpr int BM = 128, BN = 128, BK = 32, LDP = BK + 8;
  __shared__ short As[BM * LDP];
  __shared__ short Bs[BN * LDP];
  const int bm = blockIdx.x, bn = blockIdx.y;
  const int tid = threadIdx.x;
  const int lane = tid & 63, wid = tid >> 6;
  const int wm = wid >> 1, wn = wid & 1;
  const int lr = lane & 15, lh = lane >> 4;

  f32x4 acc[4][4] = {};

  const short* Abase = A + (size_t)(bm * BM) * K;
  const short* Bbase = Bt + (size_t)(bn * BN) * K;

  for (int k0 = 0; k0 < K; k0 += BK) {
    __syncthreads();
#pragma unroll
    for (int i = 0; i < 2; ++i) {
      int c = tid + i * 256;
      int row = c >> 2, col = (c & 3) << 3;
      *reinterpret_cast<short8*>(&As[row * LDP + col]) =
          *reinterpret_cast<const short8*>(Abase + (size_t)row * K + k0 + col);
      *reinterpret_cast<short8*>(&Bs[row * LDP + col]) =
          *reinterpret_cast<const short8*>(Bbase + (size_t)row * K + k0 + col);
    }
    __syncthreads();

    short8 af[4], bfr[4];
#pragma unroll
    for (int m = 0; m < 4; ++m)
      af[m] = *reinterpret_cast<const short8*>(
          &As[(wm * 64 + m * 16 + lr) * LDP + lh * 8]);
#pragma unroll
    for (int n = 0; n < 4; ++n)
      bfr[n] = *reinterpret_cast<const short8*>(
          &Bs[(wn * 64 + n * 16 + lr) * LDP + lh * 8]);
#pragma unroll
    for (int m = 0; m < 4; ++m)
#pragma unroll
      for (int n = 0; n < 4; ++n)
        acc[m][n] = mfma16(af[m], bfr[n], acc[m][n]);
  }

  // C/D layout: col = lane&15, row = 4*(lane>>4)+r
#pragma unroll
  for (int m = 0; m < 4; ++m) {
#pragma unroll
    for (int n = 0; n < 4; ++n) {
#pragma unroll
      for (int r = 0; r < 4; ++r) {
        int row = bm * BM + wm * 64 + m * 16 + lh * 4 + r;
        int col = bn * BN + wn * 64 + n * 16 + lr;
        float v = acc[m][n][r] + bias[col];
        if (MODE == 0) {
          Cf[(size_t)row * N + col] = v;
        } else {
          if (bn < 12) {  // Q,K region (boundary 1536 is tile-aligned)
            qk_out[(size_t)row * N_QK + col] = f2bf(v);
          } else {        // V region -> transposed store
            int hd_ = col - N_QK;
            int h = hd_ >> 6, d = hd_ & 63;
            int b_ = row >> 12, t_ = row & (T - 1);
            vt_out[(size_t)((b_ * NH + h) * HD + d) * T + t_] = f2bf(v);
          }
        }
      }
    }
  }
}

// ---------------------------------------------------------------------------
// Causal flash attention.
// Grid: (T/128, B*H), heavy q-blocks first. Block: 256 thr = 4 waves.
// Wave owns 32 q-rows (2 m-tiles of 16). K row-major + V^T staged in LDS
// (both via coalesced b128), KVBLK=64. DPP softmax. P via per-wave LDS.
// Scale 1/8 folded into Q.
// ---------------------------------------------------------------------------
__global__ __launch_bounds__(256, 3)
void attn_kernel(const short* __restrict__ qk, const short* __restrict__ vt,
                 short* __restrict__ y) {
  constexpr int LKD = HD + 8;  // 72 shorts = 144 B rows
  __shared__ short K_lds[64 * LKD];
  __shared__ short Vt_lds[64 * LKD];      // [d][k]
  __shared__ short P_lds[4 * 32 * LKD];   // per-wave P[32][64]

  const int qb = 31 - (int)blockIdx.x;    // heavy blocks first
  const int bh = blockIdx.y;
  const int b = bh / NH, h = bh % NH;
  const int tid = threadIdx.x, wid = tid >> 6, lane = tid & 63;
  const int lr = lane & 15, lh = lane >> 4;
  const int qbase = qb * 128 + wid * 32;

  const short* qk_b  = qk + (size_t)b * T * N_QK;
  const short* vt_bh = vt + (size_t)(bh * HD) * T;

  // Q fragments (A-frag: row=lane&15, k=8*(lane>>4)+i), pre-scaled by 1/8
  short8 qf[2][2];
#pragma unroll
  for (int m = 0; m < 2; ++m) {
    const short* qp =
        qk_b + (size_t)(qbase + m * 16 + lr) * N_QK + h * HD + lh * 8;
#pragma unroll
    for (int ch = 0; ch < 2; ++ch) {
      short8 raw = *reinterpret_cast<const short8*>(qp + ch * 32);
#pragma unroll
      for (int i = 0; i < 8; ++i) raw[i] = f2bf(bf2f(raw[i]) * 0.125f);
      qf[m][ch] = raw;
    }
  }

  f32x4 oacc[2][4] = {};
  float mrow[2][4], lrow[2][4];
#pragma unroll
  for (int m = 0; m < 2; ++m)
#pragma unroll
    for (int r = 0; r < 4; ++r) { mrow[m][r] = -1e30f; lrow[m][r] = 0.f; }

  short* pl = &P_lds[wid * 32 * LKD];

  const int nkb = 2 * qb + 2;
  for (int kb = 0; kb < nkb; ++kb) {
    __syncthreads();  // previous tile's readers done
#pragma unroll
    for (int i = 0; i < 2; ++i) {  // stage K [k][d] and V^T [d][k]
      int c = tid + i * 256;
      int row = c >> 3, col = (c & 7) << 3;
      *reinterpret_cast<short8*>(&K_lds[row * LKD + col]) =
          *reinterpret_cast<const short8*>(
              qk_b + (size_t)(kb * 64 + row) * N_QK + CDIM + h * HD + col);
      *reinterpret_cast<short8*>(&Vt_lds[row * LKD + col]) =
          *reinterpret_cast<const short8*>(vt_bh + (size_t)row * T + kb * 64 +
                                           col);
    }
    __syncthreads();

    // wave fully above the causal diagonal for this k-block? (wave-uniform)
    if (kb * 64 > qbase + 31) continue;

    // S[2m][16 q][64 k] = Q @ K^T
    f32x4 s[2][4];
#pragma unroll
    for (int kt = 0; kt < 4; ++kt) {
      short8 kf0 = *reinterpret_cast<const short8*>(
          &K_lds[(kt * 16 + lr) * LKD + lh * 8]);
      short8 kf1 = *reinterpret_cast<const short8*>(
          &K_lds[(kt * 16 + lr) * LKD + 32 + lh * 8]);
#pragma unroll
      for (int m = 0; m < 2; ++m) {
        f32x4 z = {0.f, 0.f, 0.f, 0.f};
        z = mfma16(qf[m][0], kf0, z);
        z = mfma16(qf[m][1], kf1, z);
        s[m][kt] = z;
      }
    }
    if (kb * 64 + 63 > qbase) {  // diagonal region: causal mask (uniform br)
#pragma unroll
      for (int m = 0; m < 2; ++m)
#pragma unroll
        for (int kt = 0; kt < 4; ++kt)
#pragma unroll
          for (int r = 0; r < 4; ++r)
            if (kb * 64 + kt * 16 + lr > qbase + m * 16 + lh * 4 + r)
              s[m][kt][r] = -1e30f;
    }

    // online softmax; row q=4*lh+r lives on lanes lr=0..15 of DPP row lh
#pragma unroll
    for (int m = 0; m < 2; ++m) {
      float alpha[4];
#pragma unroll
      for (int r = 0; r < 4; ++r) {
        float mx = fmaxf(fmaxf(s[m][0][r], s[m][1][r]),
                         fmaxf(s[m][2][r], s[m][3][r]));
        mx = red16_max(mx);
        float mnew = fmaxf(mrow[m][r], mx);
        alpha[r] = exp2f((mrow[m][r] - mnew) * LOG2E);
        mrow[m][r] = mnew;
        float ps = 0.f;
#pragma unroll
        for (int kt = 0; kt < 4; ++kt) {
          float pv = exp2f((s[m][kt][r] - mnew) * LOG2E);
          s[m][kt][r] = pv;  // reuse s as P
          ps += pv;
        }
        ps = red16_sum(ps);
        lrow[m][r] = lrow[m][r] * alpha[r] + ps;
      }
#pragma unroll
      for (int n = 0; n < 4; ++n)
#pragma unroll
        for (int r = 0; r < 4; ++r) oacc[m][n][r] *= alpha[r];

      // P -> per-wave LDS (C-layout scatter), re-read below as A-frags
#pragma unroll
      for (int kt = 0; kt < 4; ++kt)
#pragma unroll
        for (int r = 0; r < 4; ++r)
          pl[(m * 16 + lh * 4 + r) * LKD + kt * 16 + lr] = f2bf(s[m][kt][r]);
    }
    __builtin_amdgcn_wave_barrier();

    short8 pf[2][2];
#pragma unroll
    for (int m = 0; m < 2; ++m)
#pragma unroll
      for (int ch = 0; ch < 2; ++ch)
        pf[m][ch] = *reinterpret_cast<const short8*>(
            &pl[(m * 16 + lr) * LKD + ch * 32 + lh * 8]);

    // O += P @ V  (B-frag straight from V^T rows, b128)
#pragma unroll
    for (int n = 0; n < 4; ++n) {
      short8 vf0 = *reinterpret_cast<const short8*>(
          &Vt_lds[(n * 16 + lr) * LKD + lh * 8]);
      short8 vf1 = *reinterpret_cast<const short8*>(
          &Vt_lds[(n * 16 + lr) * LKD + 32 + lh * 8]);
#pragma unroll
      for (int m = 0; m < 2; ++m) {
        oacc[m][n] = mfma16(pf[m][0], vf0, oacc[m][n]);
        oacc[m][n] = mfma16(pf[m][1], vf1, oacc[m][n]);
      }
    }
  }

  // normalize + write y (bf16 [B*T][C] head slice)
#pragma unroll
  for (int m = 0; m < 2; ++m) {
#pragma unroll
    for (int r = 0; r < 4; ++r) {
      float inv = 1.0f / lrow[m][r];
      int qrow = qbase + m * 16 + lh * 4 + r;
      short* yp = y + (size_t)(b * T + qrow) * CDIM + h * HD;
#pragma unroll
      for (int n = 0; n < 4; ++n) yp[n * 16 + lr] = f2bf(oacc[m][n][r] * inv);
    }
  }
}

// ---------------------------------------------------------------------------
extern "C" void kernel_launch(void* const* d_in, const int* in_sizes, int n_in,
                              void* d_out, int out_size, void* d_ws,
                              size_t ws_size, hipStream_t stream) {
  const float* x      = (const float*)d_in[0];
  const float* w_attn = (const float*)d_in[1];
  const float* b_attn = (const float*)d_in[2];
  const float* w_proj = (const float*)d_in[3];
  const float* b_proj = (const float*)d_in[4];
  float* out = (float*)d_out;

  // workspace (bf16 shorts), 55 MB total; y reuses xb
  short* xb   = (short*)d_ws;                        // 8192*768
  short* watT = xb + (size_t)M_TOK * CDIM;           // 2304*768
  short* wpT  = watT + (size_t)N_QKV * CDIM;         // 768*768
  short* qkB  = wpT + (size_t)CDIM * CDIM;           // 8192*1536
  short* vtB  = qkB + (size_t)M_TOK * N_QK;          // 24*64*4096
  short* yb   = xb;

  {
    int n = M_TOK * CDIM;
    cast_f32_bf16<<<n / 4 / 256, 256, 0, stream>>>(x, xb, n);
  }
  transpose_cast<<<dim3(N_QKV / 32, CDIM / 32), dim3(32, 8), 0, stream>>>(
      w_attn, watT, CDIM, N_QKV);
  transpose_cast<<<dim3(CDIM / 32, CDIM / 32), dim3(32, 8), 0, stream>>>(
      w_proj, wpT, CDIM, CDIM);

  // qkv = x @ w_attn + b_attn   (Q,K -> qkB; V -> vtB transposed)
  gemm_bt<2><<<dim3(M_TOK / 128, N_QKV / 128), 256, 0, stream>>>(
      xb, watT, b_attn, nullptr, qkB, vtB, M_TOK, N_QKV, CDIM);

  attn_kernel<<<dim3(T / 128, BATCH * NH), 256, 0, stream>>>(qkB, vtB, yb);

  // out = y @ w_proj + b_proj   (f32 out)
  gemm_bt<0><<<dim3(M_TOK / 128, CDIM / 128), 256, 0, stream>>>(
      yb, wpT, b_proj, out, nullptr, nullptr, M_TOK, CDIM, CDIM);
}

// Round 5
// 358.024 us; speedup vs baseline: 1.5130x; 1.0416x over previous
//
#include <hip/hip_runtime.h>

// ---------------------------------------------------------------------------
// CausalSelfAttention (GPT-2 style), MI355X / gfx950
//   qkv GEMM writes Q,K rows and V transposed (vt[bh][d][t])
//   flash attention: swapped-QK^T 32x32x16 MFMA, in-register softmax,
//   P-frags built via f2bf + __shfl_xor (no inline asm), K/V staged to LDS
//   by register round-trip with XOR-swizzled writes (T2, both sides in code).
// B=2 T=4096 C=768 H=12 hd=64
// ---------------------------------------------------------------------------

#define DEVFN __device__ __forceinline__

typedef __attribute__((ext_vector_type(8)))  short   short8;
typedef __attribute__((ext_vector_type(4)))  short   short4v;
typedef __attribute__((ext_vector_type(8)))  __bf16  bf16x8;
typedef __attribute__((ext_vector_type(4)))  float   f32x4;
typedef __attribute__((ext_vector_type(16))) float   f32x16;

constexpr int BATCH = 2;
constexpr int T     = 4096;
constexpr int CDIM  = 768;
constexpr int NH    = 12;
constexpr int HD    = 64;
constexpr int M_TOK = BATCH * T;   // 8192
constexpr int N_QKV = 3 * CDIM;    // 2304
constexpr int N_QK  = 2 * CDIM;    // 1536
constexpr float QSCALE = 0.125f * 1.44269504f;  // 1/sqrt(64) * log2(e)

DEVFN short f2bf(float f) {            // RNE float -> bf16 bits
  unsigned u = __builtin_bit_cast(unsigned, f);
  u += 0x7fffu + ((u >> 16) & 1u);
  return (short)(u >> 16);
}
DEVFN float bf2f(short s) {
  return __builtin_bit_cast(float, ((unsigned)(unsigned short)s) << 16);
}
DEVFN unsigned pack2(float a, float b) {  // 2 f32 -> packed bf16x2
  return (unsigned)(unsigned short)f2bf(a) |
         ((unsigned)(unsigned short)f2bf(b) << 16);
}
DEVFN f32x4 mfma16(short8 a, short8 b, f32x4 c) {
  return __builtin_amdgcn_mfma_f32_16x16x32_bf16(
      __builtin_bit_cast(bf16x8, a), __builtin_bit_cast(bf16x8, b), c, 0, 0, 0);
}
DEVFN f32x16 mfma32(short8 a, short8 b, f32x16 c) {
  return __builtin_amdgcn_mfma_f32_32x32x16_bf16(
      __builtin_bit_cast(bf16x8, a), __builtin_bit_cast(bf16x8, b), c, 0, 0, 0);
}
DEVFN short8 mk8(unsigned w0, unsigned w1, unsigned w2, unsigned w3) {
  union { unsigned u[4]; short8 s; } x;
  x.u[0] = w0; x.u[1] = w1; x.u[2] = w2; x.u[3] = w3;
  return x.s;
}

// ---------------------------------------------------------------------------
__global__ void cast_f32_bf16(const float* __restrict__ in,
                              short* __restrict__ out, int n) {
  int i = (blockIdx.x * blockDim.x + threadIdx.x) * 4;
  if (i >= n) return;
  f32x4 v = *reinterpret_cast<const f32x4*>(in + i);
  short4v o;
#pragma unroll
  for (int j = 0; j < 4; ++j) o[j] = f2bf(v[j]);
  *reinterpret_cast<short4v*>(out + i) = o;
}

__global__ void transpose_cast(const float* __restrict__ in,
                               short* __restrict__ out, int R, int Cc) {
  __shared__ float tile[32][33];
  int c0 = blockIdx.x * 32, r0 = blockIdx.y * 32;
  int tx = threadIdx.x, ty = threadIdx.y;  // block (32, 8)
#pragma unroll
  for (int j = 0; j < 32; j += 8) {
    int r = r0 + ty + j, c = c0 + tx;
    tile[ty + j][tx] = (r < R && c < Cc) ? in[(size_t)r * Cc + c] : 0.f;
  }
  __syncthreads();
#pragma unroll
  for (int j = 0; j < 32; j += 8) {
    int r = r0 + tx, c = c0 + ty + j;
    if (c < Cc && r < R) out[(size_t)c * R + r] = f2bf(tile[tx][ty + j]);
  }
}

// ---------------------------------------------------------------------------
// GEMM: C[M][N] = A[M][K] @ Bt[N][K]^T + bias[N]
// MODE 0: f32 plain output.
// MODE 2: qkv split — cols [0,1536) -> qk bf16 [M][1536];
//         cols [1536,2304) (= V) -> vt bf16 [(b*NH+h)*64+d][T] (transposed).
// ---------------------------------------------------------------------------
template <int MODE>
__global__ __launch_bounds__(256)
void gemm_bt(const short* __restrict__ A, const short* __restrict__ Bt,
             const float* __restrict__ bias, float* __restrict__ Cf,
             short* __restrict__ qk_out, short* __restrict__ vt_out,
             int M, int N, int K) {
  constexpr int BM = 128, BN = 128, BK = 32, LDP = BK + 8;
  __shared__ short As[BM * LDP];
  __shared__ short Bs[BN * LDP];
  const int bm = blockIdx.x, bn = blockIdx.y;
  const int tid = threadIdx.x;
  const int lane = tid & 63, wid = tid >> 6;
  const int wm = wid >> 1, wn = wid & 1;
  const int lr = lane & 15, lh = lane >> 4;

  f32x4 acc[4][4] = {};

  const short* Abase = A + (size_t)(bm * BM) * K;
  const short* Bbase = Bt + (size_t)(bn * BN) * K;

  for (int k0 = 0; k0 < K; k0 += BK) {
    __syncthreads();
#pragma unroll
    for (int i = 0; i < 2; ++i) {
      int c = tid + i * 256;
      int row = c >> 2, col = (c & 3) << 3;
      *reinterpret_cast<short8*>(&As[row * LDP + col]) =
          *reinterpret_cast<const short8*>(Abase + (size_t)row * K + k0 + col);
      *reinterpret_cast<short8*>(&Bs[row * LDP + col]) =
          *reinterpret_cast<const short8*>(Bbase + (size_t)row * K + k0 + col);
    }
    __syncthreads();

    short8 af[4], bfr[4];
#pragma unroll
    for (int m = 0; m < 4; ++m)
      af[m] = *reinterpret_cast<const short8*>(
          &As[(wm * 64 + m * 16 + lr) * LDP + lh * 8]);
#pragma unroll
    for (int n = 0; n < 4; ++n)
      bfr[n] = *reinterpret_cast<const short8*>(
          &Bs[(wn * 64 + n * 16 + lr) * LDP + lh * 8]);
#pragma unroll
    for (int m = 0; m < 4; ++m)
#pragma unroll
      for (int n = 0; n < 4; ++n)
        acc[m][n] = mfma16(af[m], bfr[n], acc[m][n]);
  }

  // C/D layout: col = lane&15, row = 4*(lane>>4)+r
#pragma unroll
  for (int m = 0; m < 4; ++m) {
#pragma unroll
    for (int n = 0; n < 4; ++n) {
#pragma unroll
      for (int r = 0; r < 4; ++r) {
        int row = bm * BM + wm * 64 + m * 16 + lh * 4 + r;
        int col = bn * BN + wn * 64 + n * 16 + lr;
        float v = acc[m][n][r] + bias[col];
        if (MODE == 0) {
          Cf[(size_t)row * N + col] = v;
        } else {
          if (bn < 12) {  // Q,K region (boundary 1536 is tile-aligned)
            qk_out[(size_t)row * N_QK + col] = f2bf(v);
          } else {        // V region -> transposed store
            int hd_ = col - N_QK;
            int h = hd_ >> 6, d = hd_ & 63;
            int b_ = row >> 12, t_ = row & (T - 1);
            vt_out[(size_t)((b_ * NH + h) * HD + d) * T + t_] = f2bf(v);
          }
        }
      }
    }
  }
}

// ---------------------------------------------------------------------------
// Causal flash attention, swapped-QK^T 32x32 structure (no inline asm).
// Grid: (T/128, B*H), heavy q-blocks first. Block: 256 thr = 4 waves;
// wave owns 32 q-rows. Per 32-k sub-block: S^T = mfma32(K, Q) so each lane
// holds 16 S-values of one q-column -> in-register softmax (shfl_xor 32
// partner combine) -> P packed to bf16 words, distributed to PV B-frag via
// shfl_xor + select. K[k][d], V^T[d][k] in LDS, XOR-swizzled on write AND
// read (byte ^= (row&7)<<4) — same expression both sides.
// ---------------------------------------------------------------------------
__global__ __launch_bounds__(256)
void attn_kernel(const short* __restrict__ qk, const short* __restrict__ vt,
                 short* __restrict__ y) {
  __shared__ short K_lds[64 * 64];   // [k][d], 128B rows, swizzled
  __shared__ short V_lds[64 * 64];   // [d][k], 128B rows, swizzled

  const int qb = 31 - (int)blockIdx.x;  // heavy blocks first
  const int bh = blockIdx.y;
  const int b = bh / NH, h = bh % NH;
  const int tid = threadIdx.x, wid = tid >> 6, lane = tid & 63;
  const int c31 = lane & 31, hi = lane >> 5;
  const int wq = qb * 128 + wid * 32;   // wave's first q row
  const int qabs = wq + c31;            // this lane's q column

  const short* qk_b  = qk + (size_t)b * T * N_QK;
  const short* vt_bh = vt + (size_t)(bh * HD) * T;

  // Q B-frags (lane: q=c31, d = ds*16 + 8*hi + i), scaled by QSCALE
  short8 qf[4];
  {
    const short* qp = qk_b + (size_t)qabs * N_QK + h * HD;
#pragma unroll
    for (int ds = 0; ds < 4; ++ds) {
      short8 raw = *reinterpret_cast<const short8*>(qp + ds * 16 + hi * 8);
#pragma unroll
      for (int i = 0; i < 8; ++i) raw[i] = f2bf(bf2f(raw[i]) * QSCALE);
      qf[ds] = raw;
    }
  }

  f32x16 oacc[2];
#pragma unroll
  for (int dt = 0; dt < 2; ++dt)
#pragma unroll
    for (int r = 0; r < 16; ++r) oacc[dt][r] = 0.f;
  float mrow = -1e30f, lrow = 0.f;

  const int nkb = 2 * qb + 2;
  for (int kb = 0; kb < nkb; ++kb) {
    __syncthreads();  // previous tile's readers done
    // stage K [k][d] and V^T [d][k]; XOR-swizzle applied on the WRITE addr.
#pragma unroll
    for (int j = 0; j < 2; ++j) {
      int ck = j * 256 + tid;                // 16B-chunk id
      int row = ck >> 3;
      int colB = (ck & 7) << 4;              // logical byte col 0..112
      int swzB = colB ^ ((row & 7) << 4);    // physical byte col
      short8 kv = *reinterpret_cast<const short8*>(
          qk_b + (size_t)(kb * 64 + row) * N_QK + CDIM + h * HD + (colB >> 1));
      short8 vv = *reinterpret_cast<const short8*>(
          vt_bh + (size_t)row * T + kb * 64 + (colB >> 1));
      *reinterpret_cast<short8*>(&K_lds[(row * 128 + swzB) >> 1]) = kv;
      *reinterpret_cast<short8*>(&V_lds[(row * 128 + swzB) >> 1]) = vv;
    }
    __syncthreads();

    if (kb * 64 > wq + 31) continue;  // wave fully above causal diagonal

#pragma unroll
    for (int kk = 0; kk < 2; ++kk) {
      const int ks = kb * 64 + kk * 32;
      if (ks > wq + 31) continue;

      // S^T[32k][32q]: lane holds k-rows (r&3)+8*(r>>2)+4*hi, q = c31
      f32x16 s;
#pragma unroll
      for (int r = 0; r < 16; ++r) s[r] = 0.f;
#pragma unroll
      for (int ds = 0; ds < 4; ++ds) {
        short8 kf = *reinterpret_cast<const short8*>(
            &K_lds[((kk * 32 + c31) * 128 +
                    ((ds * 32 + hi * 16) ^ ((c31 & 7) << 4))) >> 1]);
        s = mfma32(kf, qf[ds], s);
      }

      if (ks + 31 > wq) {  // causal mask (wave-uniform branch)
#pragma unroll
        for (int r = 0; r < 16; ++r) {
          int kab = ks + (r & 3) + 8 * (r >> 2) + 4 * hi;
          if (kab > qabs) s[r] = -1e30f;
        }
      }

      // online softmax, exp2 domain (log2e folded into Q)
      float mx = s[0];
#pragma unroll
      for (int r = 1; r < 16; ++r) mx = fmaxf(mx, s[r]);
      mx = fmaxf(mx, __shfl_xor(mx, 32));
      float mnew = fmaxf(mrow, mx);
      float alpha = exp2f(mrow - mnew);
      mrow = mnew;
      float p[16], psum = 0.f;
#pragma unroll
      for (int r = 0; r < 16; ++r) { p[r] = exp2f(s[r] - mnew); psum += p[r]; }
      psum += __shfl_xor(psum, 32);
      lrow = lrow * alpha + psum;
#pragma unroll
      for (int dt = 0; dt < 2; ++dt)
#pragma unroll
        for (int r = 0; r < 16; ++r) oacc[dt][r] *= alpha;

      // P -> bf16 PV B-frags. Lane holds (kt slice, k rel to kt*16):
      //   lo: p[8kt+0..3]=k0..3,  p[8kt+4..7]=k8..11
      //   hi: p[8kt+0..3]=k4..7,  p[8kt+4..7]=k12..15
      // B-frag word w = (k_{8hi+2w}, k_{8hi+2w+1}):
      //   w0 = hi ? partner(C) : A      A=pack(p0,p1)  C=pack(p4,p5)
      //   w1 = hi ? partner(D) : B      B=pack(p2,p3)  D=pack(p6,p7)
      //   w2 = hi ? C : partner(A)
      //   w3 = hi ? D : partner(B)
#pragma unroll
      for (int kt = 0; kt < 2; ++kt) {
        unsigned Aw = pack2(p[8 * kt + 0], p[8 * kt + 1]);
        unsigned Bw = pack2(p[8 * kt + 2], p[8 * kt + 3]);
        unsigned Cw = pack2(p[8 * kt + 4], p[8 * kt + 5]);
        unsigned Dw = pack2(p[8 * kt + 6], p[8 * kt + 7]);
        unsigned As = __shfl_xor(Aw, 32);
        unsigned Bs = __shfl_xor(Bw, 32);
        unsigned Cs = __shfl_xor(Cw, 32);
        unsigned Ds = __shfl_xor(Dw, 32);
        short8 pf = mk8(hi ? Cs : Aw, hi ? Ds : Bw, hi ? Cw : As,
                        hi ? Dw : Bs);
        // O^T[d][q] += V^T-frag (A) x P-frag (B)
#pragma unroll
        for (int dt = 0; dt < 2; ++dt) {
          short8 vf = *reinterpret_cast<const short8*>(
              &V_lds[((dt * 32 + c31) * 128 +
                      ((kk * 64 + kt * 32 + hi * 16) ^ ((c31 & 7) << 4))) >>
                     1]);
          oacc[dt] = mfma32(vf, pf, oacc[dt]);
        }
      }
    }
  }

  // epilogue: O^T reg r -> d = dt*32 + (r&3) + 8*(r>>2) + 4*hi, q = c31
  float inv = 1.0f / lrow;
  short* yp = y + (size_t)(b * T + qabs) * CDIM + h * HD;
#pragma unroll
  for (int dt = 0; dt < 2; ++dt) {
#pragma unroll
    for (int qd = 0; qd < 4; ++qd) {
      short4v o4;
#pragma unroll
      for (int e = 0; e < 4; ++e) o4[e] = f2bf(oacc[dt][4 * qd + e] * inv);
      *reinterpret_cast<short4v*>(yp + dt * 32 + qd * 8 + hi * 4) = o4;
    }
  }
}

// ---------------------------------------------------------------------------
extern "C" void kernel_launch(void* const* d_in, const int* in_sizes, int n_in,
                              void* d_out, int out_size, void* d_ws,
                              size_t ws_size, hipStream_t stream) {
  const float* x      = (const float*)d_in[0];
  const float* w_attn = (const float*)d_in[1];
  const float* b_attn = (const float*)d_in[2];
  const float* w_proj = (const float*)d_in[3];
  const float* b_proj = (const float*)d_in[4];
  float* out = (float*)d_out;

  // workspace (bf16 shorts); y reuses xb (dead after QKV GEMM)
  short* xb   = (short*)d_ws;                        // 8192*768
  short* watT = xb + (size_t)M_TOK * CDIM;           // 2304*768
  short* wpT  = watT + (size_t)N_QKV * CDIM;         // 768*768
  short* qkB  = wpT + (size_t)CDIM * CDIM;           // 8192*1536
  short* vtB  = qkB + (size_t)M_TOK * N_QK;          // 24*64*4096
  short* yb   = xb;

  {
    int n = M_TOK * CDIM;
    cast_f32_bf16<<<n / 4 / 256, 256, 0, stream>>>(x, xb, n);
  }
  transpose_cast<<<dim3(N_QKV / 32, CDIM / 32), dim3(32, 8), 0, stream>>>(
      w_attn, watT, CDIM, N_QKV);
  transpose_cast<<<dim3(CDIM / 32, CDIM / 32), dim3(32, 8), 0, stream>>>(
      w_proj, wpT, CDIM, CDIM);

  // qkv = x @ w_attn + b_attn   (Q,K -> qkB; V -> vtB transposed)
  gemm_bt<2><<<dim3(M_TOK / 128, N_QKV / 128), 256, 0, stream>>>(
      xb, watT, b_attn, nullptr, qkB, vtB, M_TOK, N_QKV, CDIM);

  attn_kernel<<<dim3(T / 128, BATCH * NH), 256, 0, stream>>>(qkB, vtB, yb);

  // out = y @ w_proj + b_proj   (f32 out)
  gemm_bt<0><<<dim3(M_TOK / 128, CDIM / 128), 256, 0, stream>>>(
      yb, wpT, b_proj, out, nullptr, nullptr, M_TOK, CDIM, CDIM);
}

// Round 6
// 262.749 us; speedup vs baseline: 2.0616x; 1.3626x over previous
//
#include <hip/hip_runtime.h>

// ---------------------------------------------------------------------------
// CausalSelfAttention (GPT-2 style), MI355X / gfx950
//   qkv GEMM writes Q,K rows and V transposed (vt[bh][d][t])
//   flash attention: swapped-QK^T 32x32x16 MFMA, in-register softmax,
//   paired q-tiles (heavy+light) per block for perfect balance, register
//   prefetch of next K/V tile, softmax at 64-k granularity.
// B=2 T=4096 C=768 H=12 hd=64
// ---------------------------------------------------------------------------

#define DEVFN __device__ __forceinline__

typedef __attribute__((ext_vector_type(8)))  short   short8;
typedef __attribute__((ext_vector_type(4)))  short   short4v;
typedef __attribute__((ext_vector_type(8)))  __bf16  bf16x8;
typedef __attribute__((ext_vector_type(4)))  float   f32x4;
typedef __attribute__((ext_vector_type(16))) float   f32x16;

constexpr int BATCH = 2;
constexpr int T     = 4096;
constexpr int CDIM  = 768;
constexpr int NH    = 12;
constexpr int HD    = 64;
constexpr int M_TOK = BATCH * T;   // 8192
constexpr int N_QKV = 3 * CDIM;    // 2304
constexpr int N_QK  = 2 * CDIM;    // 1536
constexpr float QSCALE = 0.125f * 1.44269504f;  // 1/sqrt(64) * log2(e)

DEVFN short f2bf(float f) {            // RNE float -> bf16 bits
  unsigned u = __builtin_bit_cast(unsigned, f);
  u += 0x7fffu + ((u >> 16) & 1u);
  return (short)(u >> 16);
}
DEVFN float bf2f(short s) {
  return __builtin_bit_cast(float, ((unsigned)(unsigned short)s) << 16);
}
DEVFN unsigned pack2(float a, float b) {  // 2 f32 -> packed bf16x2
  return (unsigned)(unsigned short)f2bf(a) |
         ((unsigned)(unsigned short)f2bf(b) << 16);
}
DEVFN f32x4 mfma16(short8 a, short8 b, f32x4 c) {
  return __builtin_amdgcn_mfma_f32_16x16x32_bf16(
      __builtin_bit_cast(bf16x8, a), __builtin_bit_cast(bf16x8, b), c, 0, 0, 0);
}
DEVFN f32x16 mfma32(short8 a, short8 b, f32x16 c) {
  return __builtin_amdgcn_mfma_f32_32x32x16_bf16(
      __builtin_bit_cast(bf16x8, a), __builtin_bit_cast(bf16x8, b), c, 0, 0, 0);
}
DEVFN short8 mk8(unsigned w0, unsigned w1, unsigned w2, unsigned w3) {
  union { unsigned u[4]; short8 s; } x;
  x.u[0] = w0; x.u[1] = w1; x.u[2] = w2; x.u[3] = w3;
  return x.s;
}

// ---------------------------------------------------------------------------
__global__ void cast_f32_bf16(const float* __restrict__ in,
                              short* __restrict__ out, int n) {
  int i = (blockIdx.x * blockDim.x + threadIdx.x) * 4;
  if (i >= n) return;
  f32x4 v = *reinterpret_cast<const f32x4*>(in + i);
  short4v o;
#pragma unroll
  for (int j = 0; j < 4; ++j) o[j] = f2bf(v[j]);
  *reinterpret_cast<short4v*>(out + i) = o;
}

__global__ void transpose_cast(const float* __restrict__ in,
                               short* __restrict__ out, int R, int Cc) {
  __shared__ float tile[32][33];
  int c0 = blockIdx.x * 32, r0 = blockIdx.y * 32;
  int tx = threadIdx.x, ty = threadIdx.y;  // block (32, 8)
#pragma unroll
  for (int j = 0; j < 32; j += 8) {
    int r = r0 + ty + j, c = c0 + tx;
    tile[ty + j][tx] = (r < R && c < Cc) ? in[(size_t)r * Cc + c] : 0.f;
  }
  __syncthreads();
#pragma unroll
  for (int j = 0; j < 32; j += 8) {
    int r = r0 + tx, c = c0 + ty + j;
    if (c < Cc && r < R) out[(size_t)c * R + r] = f2bf(tile[tx][ty + j]);
  }
}

// ---------------------------------------------------------------------------
// GEMM: C[M][N] = A[M][K] @ Bt[N][K]^T + bias[N]
// MODE 0: f32 plain output.
// MODE 2: qkv split — cols [0,1536) -> qk bf16 [M][1536];
//         cols [1536,2304) (= V) -> vt bf16 [(b*NH+h)*64+d][T] (transposed).
// ---------------------------------------------------------------------------
template <int MODE>
__global__ __launch_bounds__(256)
void gemm_bt(const short* __restrict__ A, const short* __restrict__ Bt,
             const float* __restrict__ bias, float* __restrict__ Cf,
             short* __restrict__ qk_out, short* __restrict__ vt_out,
             int M, int N, int K) {
  constexpr int BM = 128, BN = 128, BK = 32, LDP = BK + 8;
  __shared__ short As[BM * LDP];
  __shared__ short Bs[BN * LDP];
  const int bm = blockIdx.x, bn = blockIdx.y;
  const int tid = threadIdx.x;
  const int lane = tid & 63, wid = tid >> 6;
  const int wm = wid >> 1, wn = wid & 1;
  const int lr = lane & 15, lh = lane >> 4;

  f32x4 acc[4][4] = {};

  const short* Abase = A + (size_t)(bm * BM) * K;
  const short* Bbase = Bt + (size_t)(bn * BN) * K;

  for (int k0 = 0; k0 < K; k0 += BK) {
    __syncthreads();
#pragma unroll
    for (int i = 0; i < 2; ++i) {
      int c = tid + i * 256;
      int row = c >> 2, col = (c & 3) << 3;
      *reinterpret_cast<short8*>(&As[row * LDP + col]) =
          *reinterpret_cast<const short8*>(Abase + (size_t)row * K + k0 + col);
      *reinterpret_cast<short8*>(&Bs[row * LDP + col]) =
          *reinterpret_cast<const short8*>(Bbase + (size_t)row * K + k0 + col);
    }
    __syncthreads();

    short8 af[4], bfr[4];
#pragma unroll
    for (int m = 0; m < 4; ++m)
      af[m] = *reinterpret_cast<const short8*>(
          &As[(wm * 64 + m * 16 + lr) * LDP + lh * 8]);
#pragma unroll
    for (int n = 0; n < 4; ++n)
      bfr[n] = *reinterpret_cast<const short8*>(
          &Bs[(wn * 64 + n * 16 + lr) * LDP + lh * 8]);
#pragma unroll
    for (int m = 0; m < 4; ++m)
#pragma unroll
      for (int n = 0; n < 4; ++n)
        acc[m][n] = mfma16(af[m], bfr[n], acc[m][n]);
  }

  // C/D layout: col = lane&15, row = 4*(lane>>4)+r
#pragma unroll
  for (int m = 0; m < 4; ++m) {
#pragma unroll
    for (int n = 0; n < 4; ++n) {
#pragma unroll
      for (int r = 0; r < 4; ++r) {
        int row = bm * BM + wm * 64 + m * 16 + lh * 4 + r;
        int col = bn * BN + wn * 64 + n * 16 + lr;
        float v = acc[m][n][r] + bias[col];
        if (MODE == 0) {
          Cf[(size_t)row * N + col] = v;
        } else {
          if (bn < 12) {  // Q,K region (boundary 1536 is tile-aligned)
            qk_out[(size_t)row * N_QK + col] = f2bf(v);
          } else {        // V region -> transposed store
            int hd_ = col - N_QK;
            int h = hd_ >> 6, d = hd_ & 63;
            int b_ = row >> 12, t_ = row & (T - 1);
            vt_out[(size_t)((b_ * NH + h) * HD + d) * T + t_] = f2bf(v);
          }
        }
      }
    }
  }
}

// ---------------------------------------------------------------------------
// Causal flash attention, swapped-QK^T 32x32 structure.
// Grid: (16, B*H). Block: 256 thr = 4 waves; wave owns 32 q-rows.
// Each block processes TWO q-tiles (128 rows each): qb = 31-bx then qb = bx,
// so every block does exactly 66 k-iterations (perfect balance).
// Per 64-k tile: register-prefetched K/V staging (loads issued after the
// staging barrier, consumed next iteration), S^T = mfma32(K, Q), merged
// 64-k online softmax in registers (shfl_xor 32 partner combine), P packed
// to bf16 B-frags via shfl_xor + select. K[k][d], V^T[d][k] in LDS,
// XOR-swizzled on write AND read (byte ^= (row&7)<<4).
// ---------------------------------------------------------------------------
__global__ __launch_bounds__(256, 2)
void attn_kernel(const short* __restrict__ qk, const short* __restrict__ vt,
                 short* __restrict__ y) {
  __shared__ short K_lds[64 * 64];   // [k][d], 128B rows, swizzled
  __shared__ short V_lds[64 * 64];   // [d][k], 128B rows, swizzled

  const int bx = blockIdx.x;            // 0..15
  const int bh = blockIdx.y;
  const int b = bh / NH, h = bh % NH;
  const int tid = threadIdx.x, wid = tid >> 6, lane = tid & 63;
  const int c31 = lane & 31, hi = lane >> 5;

  const short* qk_b  = qk + (size_t)b * T * N_QK;
  const short* vt_bh = vt + (size_t)(bh * HD) * T;

  // staging geometry (loop-invariant): 2 chunks of 16B per thread per tile
  const int ck0 = tid, ck1 = 256 + tid;
  const int row0 = ck0 >> 3, colB0 = (ck0 & 7) << 4;
  const int row1 = ck1 >> 3, colB1 = (ck1 & 7) << 4;
  const int lsw0 = (row0 * 128 + (colB0 ^ ((row0 & 7) << 4))) >> 1;
  const int lsw1 = (row1 * 128 + (colB1 ^ ((row1 & 7) << 4))) >> 1;
  const short* kp0 = qk_b + (size_t)row0 * N_QK + CDIM + h * HD + (colB0 >> 1);
  const short* kp1 = qk_b + (size_t)row1 * N_QK + CDIM + h * HD + (colB1 >> 1);
  const short* vp0 = vt_bh + (size_t)row0 * T + (colB0 >> 1);
  const short* vp1 = vt_bh + (size_t)row1 * T + (colB1 >> 1);

  const int swq = (c31 & 7) << 4;       // read-side swizzle XOR (bytes)

  for (int ph = 0; ph < 2; ++ph) {
    const int qb = ph ? bx : 31 - bx;   // heavy tile first
    const int wq = qb * 128 + wid * 32; // wave's first q row
    const int qabs = wq + c31;          // lane's q column

    // Q B-frags (lane: q=c31, d = ds*16 + 8*hi + i), scaled by QSCALE
    short8 qf[4];
    {
      const short* qp = qk_b + (size_t)qabs * N_QK + h * HD;
#pragma unroll
      for (int ds = 0; ds < 4; ++ds) {
        short8 raw = *reinterpret_cast<const short8*>(qp + ds * 16 + hi * 8);
#pragma unroll
        for (int i = 0; i < 8; ++i) raw[i] = f2bf(bf2f(raw[i]) * QSCALE);
        qf[ds] = raw;
      }
    }

    f32x16 oacc[2];
#pragma unroll
    for (int dt = 0; dt < 2; ++dt)
#pragma unroll
      for (int r = 0; r < 16; ++r) oacc[dt][r] = 0.f;
    float mrow = -1e30f, lrow = 0.f;

    const int nkb = 2 * qb + 2;

    // prologue: prefetch tile 0 into registers
    short8 kreg0 = *reinterpret_cast<const short8*>(kp0);
    short8 kreg1 = *reinterpret_cast<const short8*>(kp1);
    short8 vreg0 = *reinterpret_cast<const short8*>(vp0);
    short8 vreg1 = *reinterpret_cast<const short8*>(vp1);

    for (int kbt = 0; kbt < nkb; ++kbt) {
      __syncthreads();  // previous tile's readers done; prefetch landed
      *reinterpret_cast<short8*>(&K_lds[lsw0]) = kreg0;
      *reinterpret_cast<short8*>(&K_lds[lsw1]) = kreg1;
      *reinterpret_cast<short8*>(&V_lds[lsw0]) = vreg0;
      *reinterpret_cast<short8*>(&V_lds[lsw1]) = vreg1;
      __syncthreads();  // tile visible
      if (kbt + 1 < nkb) {  // issue next-tile loads; land during compute
        size_t ko = (size_t)(kbt + 1) * 64 * N_QK;
        int    vo = (kbt + 1) * 64;
        kreg0 = *reinterpret_cast<const short8*>(kp0 + ko);
        kreg1 = *reinterpret_cast<const short8*>(kp1 + ko);
        vreg0 = *reinterpret_cast<const short8*>(vp0 + vo);
        vreg1 = *reinterpret_cast<const short8*>(vp1 + vo);
      }

      const int ks = kbt * 64;
      if (ks > wq + 31) continue;  // wave fully above causal diagonal

      // S^T[64k][32q]: lane holds k-rows ks + 32*kk + (r&3)+8*(r>>2)+4*hi
      f32x16 s0, s1;
#pragma unroll
      for (int r = 0; r < 16; ++r) { s0[r] = 0.f; s1[r] = 0.f; }
#pragma unroll
      for (int ds = 0; ds < 4; ++ds) {
        int cB = (ds * 32 + hi * 16) ^ swq;
        short8 kf0 = *reinterpret_cast<const short8*>(
            &K_lds[(c31 * 128 + cB) >> 1]);
        short8 kf1 = *reinterpret_cast<const short8*>(
            &K_lds[((32 + c31) * 128 + cB) >> 1]);
        s0 = mfma32(kf0, qf[ds], s0);
        s1 = mfma32(kf1, qf[ds], s1);
      }

      if (ks + 63 > wq) {  // causal mask (wave-uniform branch)
#pragma unroll
        for (int r = 0; r < 16; ++r) {
          int kab = ks + (r & 3) + 8 * (r >> 2) + 4 * hi;
          if (kab > qabs) s0[r] = -1e30f;
          if (kab + 32 > qabs) s1[r] = -1e30f;
        }
      }

      // merged 64-k online softmax, exp2 domain (log2e folded into Q)
      float mx = fmaxf(s0[0], s1[0]);
#pragma unroll
      for (int r = 1; r < 16; ++r) mx = fmaxf(mx, fmaxf(s0[r], s1[r]));
      mx = fmaxf(mx, __shfl_xor(mx, 32));
      float mnew = fmaxf(mrow, mx);
      float alpha = exp2f(mrow - mnew);
      mrow = mnew;
      float psum = 0.f;
#pragma unroll
      for (int r = 0; r < 16; ++r) { s0[r] = exp2f(s0[r] - mnew); psum += s0[r]; }
#pragma unroll
      for (int r = 0; r < 16; ++r) { s1[r] = exp2f(s1[r] - mnew); psum += s1[r]; }
      psum += __shfl_xor(psum, 32);
      lrow = lrow * alpha + psum;
#pragma unroll
      for (int dt = 0; dt < 2; ++dt)
#pragma unroll
        for (int r = 0; r < 16; ++r) oacc[dt][r] *= alpha;

      // P -> bf16 PV B-frags (16 k per KT slice). Lane holds (rel to KT*16):
      //   lo: k0..3 = p[b..b+3], k8..11 = p[b+4..b+7]
      //   hi: k4..7 = p[b..b+3], k12..15 = p[b+4..b+7]
      // word w = (k_{8hi+2w}, k_{8hi+2w+1}):
      //   w0 = hi?partner(C):A   w1 = hi?partner(D):B
      //   w2 = hi?C:partner(A)   w3 = hi?D:partner(B)
#pragma unroll
      for (int KT = 0; KT < 4; ++KT) {
        const f32x16& p = (KT < 2) ? s0 : s1;
        const int bse = (KT & 1) * 8;
        unsigned Aw = pack2(p[bse + 0], p[bse + 1]);
        unsigned Bw = pack2(p[bse + 2], p[bse + 3]);
        unsigned Cw = pack2(p[bse + 4], p[bse + 5]);
        unsigned Dw = pack2(p[bse + 6], p[bse + 7]);
        unsigned As = __shfl_xor(Aw, 32);
        unsigned Bs = __shfl_xor(Bw, 32);
        unsigned Cs = __shfl_xor(Cw, 32);
        unsigned Ds = __shfl_xor(Dw, 32);
        short8 pf = mk8(hi ? Cs : Aw, hi ? Ds : Bw, hi ? Cw : As,
                        hi ? Dw : Bs);
        int cB = (KT * 32 + hi * 16) ^ swq;
#pragma unroll
        for (int dt = 0; dt < 2; ++dt) {
          short8 vf = *reinterpret_cast<const short8*>(
              &V_lds[((dt * 32 + c31) * 128 + cB) >> 1]);
          oacc[dt] = mfma32(vf, pf, oacc[dt]);
        }
      }
    }

    // epilogue: O^T reg r -> d = dt*32 + (r&3) + 8*(r>>2) + 4*hi, q = c31
    float inv = 1.0f / lrow;
    short* yp = y + (size_t)(b * T + qabs) * CDIM + h * HD;
#pragma unroll
    for (int dt = 0; dt < 2; ++dt) {
#pragma unroll
      for (int qd = 0; qd < 4; ++qd) {
        short4v o4;
#pragma unroll
        for (int e = 0; e < 4; ++e) o4[e] = f2bf(oacc[dt][4 * qd + e] * inv);
        *reinterpret_cast<short4v*>(yp + dt * 32 + qd * 8 + hi * 4) = o4;
      }
    }
  }
}

// ---------------------------------------------------------------------------
extern "C" void kernel_launch(void* const* d_in, const int* in_sizes, int n_in,
                              void* d_out, int out_size, void* d_ws,
                              size_t ws_size, hipStream_t stream) {
  const float* x      = (const float*)d_in[0];
  const float* w_attn = (const float*)d_in[1];
  const float* b_attn = (const float*)d_in[2];
  const float* w_proj = (const float*)d_in[3];
  const float* b_proj = (const float*)d_in[4];
  float* out = (float*)d_out;

  // workspace (bf16 shorts); y reuses xb (dead after QKV GEMM)
  short* xb   = (short*)d_ws;                        // 8192*768
  short* watT = xb + (size_t)M_TOK * CDIM;           // 2304*768
  short* wpT  = watT + (size_t)N_QKV * CDIM;         // 768*768
  short* qkB  = wpT + (size_t)CDIM * CDIM;           // 8192*1536
  short* vtB  = qkB + (size_t)M_TOK * N_QK;          // 24*64*4096
  short* yb   = xb;

  {
    int n = M_TOK * CDIM;
    cast_f32_bf16<<<n / 4 / 256, 256, 0, stream>>>(x, xb, n);
  }
  transpose_cast<<<dim3(N_QKV / 32, CDIM / 32), dim3(32, 8), 0, stream>>>(
      w_attn, watT, CDIM, N_QKV);
  transpose_cast<<<dim3(CDIM / 32, CDIM / 32), dim3(32, 8), 0, stream>>>(
      w_proj, wpT, CDIM, CDIM);

  // qkv = x @ w_attn + b_attn   (Q,K -> qkB; V -> vtB transposed)
  gemm_bt<2><<<dim3(M_TOK / 128, N_QKV / 128), 256, 0, stream>>>(
      xb, watT, b_attn, nullptr, qkB, vtB, M_TOK, N_QKV, CDIM);

  attn_kernel<<<dim3(16, BATCH * NH), 256, 0, stream>>>(qkB, vtB, yb);

  // out = y @ w_proj + b_proj   (f32 out)
  gemm_bt<0><<<dim3(M_TOK / 128, CDIM / 128), 256, 0, stream>>>(
      yb, wpT, b_proj, out, nullptr, nullptr, M_TOK, CDIM, CDIM);
}